// Round 4
// baseline (70.759 us; speedup 1.0000x reference)
//
#include <hip/hip_runtime.h>
#include <hip/hip_bf16.h>

#define BATCH 4096
#define DIM   512
#define NLBL  512
#define BIGF  1e4f
#define MARGIN 1.0f

#define BM 128        // super-tile (2x2 waves of 64x64)
#define NT (BATCH/BM) // 32
#define NPAIR (NT*(NT+1)/2)  // 528

using f32x4  = __attribute__((ext_vector_type(4))) float;
using bf16x8 = __attribute__((ext_vector_type(8))) short;

__device__ __forceinline__ unsigned short f2bf(float x) {
    __hip_bfloat16 h = __float2bfloat16(x);
    return *reinterpret_cast<unsigned short*>(&h);
}

// ---------------- kernel 1: row L2-normalize -> bf16 (+ hp/hn init fused) ----------------
__global__ __launch_bounds__(256) void normalize_k(const float* __restrict__ emb,
                                                   unsigned short* __restrict__ Hi,
                                                   unsigned* __restrict__ hp,
                                                   unsigned* __restrict__ hn) {
    int wave = threadIdx.x >> 6;
    int lane = threadIdx.x & 63;
    int row  = blockIdx.x * 4 + wave;
    const float4* src = (const float4*)(emb + (size_t)row * DIM);
    float4 v0 = src[lane * 2];
    float4 v1 = src[lane * 2 + 1];
    float ss = v0.x*v0.x + v0.y*v0.y + v0.z*v0.z + v0.w*v0.w
             + v1.x*v1.x + v1.y*v1.y + v1.z*v1.z + v1.w*v1.w;
    #pragma unroll
    for (int off = 1; off < 64; off <<= 1) ss += __shfl_xor(ss, off);
    float scale = 1.0f / fmaxf(sqrtf(ss), 1e-12f);
    bf16x8 o;
    o[0] = (short)f2bf(v0.x * scale);
    o[1] = (short)f2bf(v0.y * scale);
    o[2] = (short)f2bf(v0.z * scale);
    o[3] = (short)f2bf(v0.w * scale);
    o[4] = (short)f2bf(v1.x * scale);
    o[5] = (short)f2bf(v1.y * scale);
    o[6] = (short)f2bf(v1.z * scale);
    o[7] = (short)f2bf(v1.w * scale);
    *(bf16x8*)(Hi + (size_t)row * DIM + lane * 8) = o;
    if (lane == 0) {
        hp[row] = 0u;
        hn[row] = __float_as_uint(BIGF);
    }
}

// ---------------- kernel 2: fused bf16 MFMA sim + batch-hard mining ----------------
// Barrier-free K-loop: MFMA fragments loaded directly global->VGPR (L2-resident
// Hi), register double-buffered. 4 waves = 2x2 quadrants of a 128x128 tile.
__global__ __launch_bounds__(256) void mine_k(const unsigned short* __restrict__ Hi,
                                              const int* __restrict__ lab,
                                              unsigned* __restrict__ hp,
                                              unsigned* __restrict__ hn) {
    __shared__ float rowp[2][BM], rown[2][BM], colp[2][BM], coln[2][BM]; // 4 KB

    // XCD-aware swizzle (528 = 8*66, bijective)
    int p = (int)blockIdx.x;
    p = (p & 7) * (NPAIR / 8) + (p >> 3);
    int bi = 0, rem = p;
    while (rem >= NT - bi) { rem -= NT - bi; ++bi; }
    int bj = bi + rem;
    const int i0 = bi * BM;
    const int j0 = bj * BM;

    const int tid  = threadIdx.x;
    const int w    = tid >> 6;
    const int lane = tid & 63;
    const int wr   = w >> 1;
    const int wc   = w & 1;
    const int l15  = lane & 15;
    const int lhi  = lane >> 4;

    // labels (hoisted; overlap with first loads)
    int lj[4];
    #pragma unroll
    for (int n = 0; n < 4; ++n) lj[n] = lab[j0 + wc * 64 + n * 16 + l15];
    int li[16];
    #pragma unroll
    for (int m = 0; m < 4; ++m)
        #pragma unroll
        for (int r = 0; r < 4; ++r)
            li[m * 4 + r] = lab[i0 + wr * 64 + m * 16 + lhi * 4 + r];

    // per-lane fragment base pointers: row (l15), k-chunk (lhi*8)
    const unsigned short* Ab = Hi + (size_t)(i0 + wr * 64 + l15) * DIM + lhi * 8;
    const unsigned short* Bb = Hi + (size_t)(j0 + wc * 64 + l15) * DIM + lhi * 8;

    f32x4 acc[4][4] = {};

    bf16x8 a0[4], b0[4], a1[4], b1[4];

#define LOADF(A, B, t)                                              \
    do {                                                            \
        _Pragma("unroll")                                           \
        for (int m = 0; m < 4; ++m)                                 \
            (A)[m] = *(const bf16x8*)(Ab + m * 16 * DIM + (t) * 32);\
        _Pragma("unroll")                                           \
        for (int n = 0; n < 4; ++n)                                 \
            (B)[n] = *(const bf16x8*)(Bb + n * 16 * DIM + (t) * 32);\
    } while (0)

#define MFMA_ALL(A, B)                                              \
    do {                                                            \
        _Pragma("unroll")                                           \
        for (int m = 0; m < 4; ++m)                                 \
            _Pragma("unroll")                                       \
            for (int n = 0; n < 4; ++n)                             \
                acc[m][n] = __builtin_amdgcn_mfma_f32_16x16x32_bf16((A)[m], (B)[n], acc[m][n], 0, 0, 0); \
    } while (0)

    LOADF(a0, b0, 0);
    #pragma unroll
    for (int t = 0; t < (DIM / 32) - 1; ++t) {   // 15 iters, static parity
        if ((t & 1) == 0) { LOADF(a1, b1, t + 1); MFMA_ALL(a0, b0); }
        else              { LOADF(a0, b0, t + 1); MFMA_ALL(a1, b1); }
    }
    MFMA_ALL(a1, b1);   // t = 15 fragments live in a1/b1 (15 odd)

#undef LOADF
#undef MFMA_ALL

    // ---- epilogue ----
    // C[i][j]: i = i0 + wr*64 + m*16 + lhi*4 + r ; j = j0 + wc*64 + n*16 + l15
    #pragma unroll
    for (int m = 0; m < 4; ++m) {
        #pragma unroll
        for (int r = 0; r < 4; ++r) {
            int i   = i0 + wr * 64 + m * 16 + lhi * 4 + r;
            int lir = li[m * 4 + r];
            float pm = 0.0f, nm = BIGF;
            #pragma unroll
            for (int n = 0; n < 4; ++n) {
                float dist = fmaxf(1.0f - acc[m][n][r], 0.0f);
                int j = j0 + wc * 64 + n * 16 + l15;
                if (lir == lj[n]) {
                    if (i != j) pm = fmaxf(pm, dist);
                } else {
                    nm = fminf(nm, dist);
                }
            }
            #pragma unroll
            for (int off = 1; off < 16; off <<= 1) {
                pm = fmaxf(pm, __shfl_xor(pm, off));
                nm = fminf(nm, __shfl_xor(nm, off));
            }
            if (l15 == 0) {
                int loc = wr * 64 + m * 16 + lhi * 4 + r;
                rowp[wc][loc] = pm;
                rown[wc][loc] = nm;
            }
        }
    }

    #pragma unroll
    for (int n = 0; n < 4; ++n) {
        int j   = j0 + wc * 64 + n * 16 + l15;
        int ljn = lj[n];
        float cp = 0.0f, cn = BIGF;
        #pragma unroll
        for (int m = 0; m < 4; ++m) {
            #pragma unroll
            for (int r = 0; r < 4; ++r) {
                float dist = fmaxf(1.0f - acc[m][n][r], 0.0f);
                int i = i0 + wr * 64 + m * 16 + lhi * 4 + r;
                if (li[m * 4 + r] == ljn) {
                    if (i != j) cp = fmaxf(cp, dist);
                } else {
                    cn = fminf(cn, dist);
                }
            }
        }
        #pragma unroll
        for (int off = 16; off < 64; off <<= 1) {
            cp = fmaxf(cp, __shfl_xor(cp, off));
            cn = fminf(cn, __shfl_xor(cn, off));
        }
        if (lhi == 0) {
            int loc = wc * 64 + n * 16 + l15;
            colp[wr][loc] = cp;
            coln[wr][loc] = cn;
        }
    }

    __syncthreads();

    if (tid < BM) {
        float pmv = fmaxf(rowp[0][tid], rowp[1][tid]);
        float nmv = fminf(rown[0][tid], rown[1][tid]);
        atomicMax(hp + i0 + tid, __float_as_uint(pmv));
        atomicMin(hn + i0 + tid, __float_as_uint(nmv));
    } else {
        int c = tid - BM;
        float pmv = fmaxf(colp[0][c], colp[1][c]);
        float nmv = fminf(coln[0][c], coln[1][c]);
        atomicMax(hp + j0 + c, __float_as_uint(pmv));
        atomicMin(hn + j0 + c, __float_as_uint(nmv));
    }
}

// ---------------- kernel 3: finalize ----------------
__global__ __launch_bounds__(1024) void final_k(const int* __restrict__ lab,
                                                const unsigned* __restrict__ hp,
                                                const unsigned* __restrict__ hn,
                                                float* __restrict__ out) {
    __shared__ int   cnt[NLBL];
    __shared__ float ssum[16];
    __shared__ int   scnt[16];
    int t = threadIdx.x;
    for (int i = t; i < NLBL; i += 1024) cnt[i] = 0;
    __syncthreads();
    for (int i = t; i < BATCH; i += 1024) atomicAdd(&cnt[lab[i]], 1);
    __syncthreads();

    float lsum = 0.0f;
    int   lcnt = 0;
    for (int i = t; i < BATCH; i += 1024) {
        int c = cnt[lab[i]];
        if ((c > 1) && (c < BATCH)) {
            float per = fmaxf(__uint_as_float(hp[i]) - __uint_as_float(hn[i]) + MARGIN, 0.0f);
            lsum += per;
            lcnt += 1;
        }
    }
    #pragma unroll
    for (int off = 1; off < 64; off <<= 1) {
        lsum += __shfl_xor(lsum, off);
        lcnt += __shfl_xor(lcnt, off);
    }
    int w = t >> 6;
    if ((t & 63) == 0) { ssum[w] = lsum; scnt[w] = lcnt; }
    __syncthreads();
    if (t == 0) {
        float s = 0.0f; int c2 = 0;
        #pragma unroll
        for (int i = 0; i < 16; ++i) { s += ssum[i]; c2 += scnt[i]; }
        out[0] = s / (float)max(c2, 1);
    }
}

// ---------------- launcher ----------------
extern "C" void kernel_launch(void* const* d_in, const int* in_sizes, int n_in,
                              void* d_out, int out_size, void* d_ws, size_t ws_size,
                              hipStream_t stream) {
    const float* emb = (const float*)d_in[0];
    const int*   lab = (const int*)d_in[1];

    char* base = (char*)d_ws;
    unsigned short* Hi = (unsigned short*)base;                       // 4 MB
    unsigned* hp = (unsigned*)(base + (size_t)BATCH * DIM * 2);       // 16 KB
    unsigned* hn = hp + BATCH;                                        // 16 KB

    normalize_k<<<BATCH / 4, 256, 0, stream>>>(emb, Hi, hp, hn);
    mine_k<<<NPAIR, 256, 0, stream>>>(Hi, lab, hp, hn);
    final_k<<<1, 1024, 0, stream>>>(lab, hp, hn, (float*)d_out);
}

// Round 5
// 41.909 us; speedup vs baseline: 1.6884x; 1.6884x over previous
//
#include <hip/hip_runtime.h>
#include <hip/hip_bf16.h>

#define BATCH 4096
#define DIM   512
#define NLBL  512
#define BIGF  1e4f
#define MARGIN 1.0f

#define BM 128        // tile (rows = cols)
#define BK 64         // bf16 elems per K-step
#define NT (BATCH/BM) // 32
#define NPAIR (NT*(NT+1)/2)  // 528
#define KITERS (DIM/BK)      // 8

using f32x4  = __attribute__((ext_vector_type(4))) float;
using bf16x8 = __attribute__((ext_vector_type(8))) short;

__device__ __forceinline__ unsigned short f2bf(float x) {
    __hip_bfloat16 h = __float2bfloat16(x);
    return *reinterpret_cast<unsigned short*>(&h);
}

#define GLOAD16(gp, lp) \
    __builtin_amdgcn_global_load_lds((const __attribute__((address_space(1))) void*)(gp), \
                                     (__attribute__((address_space(3))) void*)(lp), 16, 0, 0)

// ---------------- kernel 1: row L2-normalize -> bf16 (+ hp/hn init fused) ----------------
__global__ __launch_bounds__(256) void normalize_k(const float* __restrict__ emb,
                                                   unsigned short* __restrict__ Hi,
                                                   unsigned* __restrict__ hp,
                                                   unsigned* __restrict__ hn) {
    int wave = threadIdx.x >> 6;
    int lane = threadIdx.x & 63;
    int row  = blockIdx.x * 4 + wave;
    const float4* src = (const float4*)(emb + (size_t)row * DIM);
    float4 v0 = src[lane * 2];
    float4 v1 = src[lane * 2 + 1];
    float ss = v0.x*v0.x + v0.y*v0.y + v0.z*v0.z + v0.w*v0.w
             + v1.x*v1.x + v1.y*v1.y + v1.z*v1.z + v1.w*v1.w;
    #pragma unroll
    for (int off = 1; off < 64; off <<= 1) ss += __shfl_xor(ss, off);
    float scale = 1.0f / fmaxf(sqrtf(ss), 1e-12f);
    bf16x8 o;
    o[0] = (short)f2bf(v0.x * scale);
    o[1] = (short)f2bf(v0.y * scale);
    o[2] = (short)f2bf(v0.z * scale);
    o[3] = (short)f2bf(v0.w * scale);
    o[4] = (short)f2bf(v1.x * scale);
    o[5] = (short)f2bf(v1.y * scale);
    o[6] = (short)f2bf(v1.z * scale);
    o[7] = (short)f2bf(v1.w * scale);
    *(bf16x8*)(Hi + (size_t)row * DIM + lane * 8) = o;
    if (lane == 0) {
        hp[row] = 0u;
        hn[row] = __float_as_uint(BIGF);
    }
}

// ---------------- kernel 2: fused bf16 MFMA sim + batch-hard mining ----------------
// Upper-triangle 128x128 tiles. Double-buffered LDS, counted-vmcnt pipeline:
// per K-step {vmcnt(8); s_barrier; compute(cur); s_barrier; refill(cur,t+2)}.
// Next buffer's 8 loads stay in flight across both barriers (T3+T4 minimum).
__global__ __launch_bounds__(256) void mine_k(const unsigned short* __restrict__ Hi,
                                              const int* __restrict__ lab,
                                              unsigned* __restrict__ hp,
                                              unsigned* __restrict__ hn) {
    __shared__ __attribute__((aligned(16))) unsigned short As[2][BM * BK]; // 32 KB
    __shared__ __attribute__((aligned(16))) unsigned short Bs[2][BM * BK]; // 32 KB
    __shared__ float rowp[2][BM], rown[2][BM], colp[2][BM], coln[2][BM];   // 4 KB

    // XCD-aware swizzle (528 = 8*66, bijective)
    int p = (int)blockIdx.x;
    p = (p & 7) * (NPAIR / 8) + (p >> 3);
    int bi = 0, rem = p;
    while (rem >= NT - bi) { rem -= NT - bi; ++bi; }
    int bj = bi + rem;
    const int i0 = bi * BM;
    const int j0 = bj * BM;

    const int tid  = threadIdx.x;
    const int w    = tid >> 6;
    const int lane = tid & 63;
    const int wr   = w >> 1;
    const int wc   = w & 1;
    const int l15  = lane & 15;
    const int lhi  = lane >> 4;
    const int l7   = lane & 7;

    const int srow = lane >> 3;               // 0..7
    const int sc   = (lane & 7) ^ (srow & 7); // pre-swizzled 16B chunk

    f32x4 acc[4][4] = {};
    const char* HiB = (const char*)Hi;

    auto STAGE = [&](int buf, int t) {
        const size_t kb = (size_t)t * (BK * 2);
        #pragma unroll
        for (int q = 0; q < 4; ++q) {
            int r8 = w * 32 + q * 8;
            const char* ga = HiB + (size_t)(i0 + r8 + srow) * (DIM * 2) + kb + (sc << 4);
            const char* gb = HiB + (size_t)(j0 + r8 + srow) * (DIM * 2) + kb + (sc << 4);
            GLOAD16(ga, (char*)As[buf] + r8 * 128);
            GLOAD16(gb, (char*)Bs[buf] + r8 * 128);
        }
    };
    auto COMPUTE = [&](int buf) {
        #pragma unroll
        for (int kk = 0; kk < 2; ++kk) {
            bf16x8 a[4], b[4];
            #pragma unroll
            for (int m = 0; m < 4; ++m) {
                int row = wr * 64 + m * 16 + l15;
                int cp  = ((kk * 4 + lhi) ^ l7);
                a[m] = *(const bf16x8*)((const char*)As[buf] + row * 128 + (cp << 4));
            }
            #pragma unroll
            for (int n = 0; n < 4; ++n) {
                int row = wc * 64 + n * 16 + l15;
                int cp  = ((kk * 4 + lhi) ^ l7);
                b[n] = *(const bf16x8*)((const char*)Bs[buf] + row * 128 + (cp << 4));
            }
            #pragma unroll
            for (int m = 0; m < 4; ++m)
                #pragma unroll
                for (int n = 0; n < 4; ++n)
                    acc[m][n] = __builtin_amdgcn_mfma_f32_16x16x32_bf16(a[m], b[n], acc[m][n], 0, 0, 0);
        }
    };

    // ---- counted-vmcnt double-buffer pipeline ----
    STAGE(0, 0);
    STAGE(1, 1);      // 16 loads in flight per wave
    #pragma unroll
    for (int t = 0; t < KITERS; ++t) {
        const int cur = t & 1;
        if (t < KITERS - 1) {
            asm volatile("s_waitcnt vmcnt(8)" ::: "memory");  // batch t landed; batch t+1 stays in flight
        } else {
            asm volatile("s_waitcnt vmcnt(0)" ::: "memory");  // final batch
        }
        __builtin_amdgcn_sched_barrier(0);
        __builtin_amdgcn_s_barrier();      // all waves: buf cur fully written
        COMPUTE(cur);
        __builtin_amdgcn_sched_barrier(0);
        __builtin_amdgcn_s_barrier();      // all waves done reading buf cur
        if (t + 2 < KITERS) STAGE(cur, t + 2);   // refill consumed buffer
    }

    // ---- labels (after K-loop so they don't pollute vmcnt counts) ----
    int lj[4];
    #pragma unroll
    for (int n = 0; n < 4; ++n) lj[n] = lab[j0 + wc * 64 + n * 16 + l15];
    int li[16];
    #pragma unroll
    for (int m = 0; m < 4; ++m)
        #pragma unroll
        for (int r = 0; r < 4; ++r)
            li[m * 4 + r] = lab[i0 + wr * 64 + m * 16 + lhi * 4 + r];

    // ---- epilogue ----
    // C[i][j]: i = i0 + wr*64 + m*16 + lhi*4 + r ; j = j0 + wc*64 + n*16 + l15
    #pragma unroll
    for (int m = 0; m < 4; ++m) {
        #pragma unroll
        for (int r = 0; r < 4; ++r) {
            int i   = i0 + wr * 64 + m * 16 + lhi * 4 + r;
            int lir = li[m * 4 + r];
            float pm = 0.0f, nm = BIGF;
            #pragma unroll
            for (int n = 0; n < 4; ++n) {
                float dist = fmaxf(1.0f - acc[m][n][r], 0.0f);
                int j = j0 + wc * 64 + n * 16 + l15;
                if (lir == lj[n]) {
                    if (i != j) pm = fmaxf(pm, dist);
                } else {
                    nm = fminf(nm, dist);
                }
            }
            #pragma unroll
            for (int off = 1; off < 16; off <<= 1) {
                pm = fmaxf(pm, __shfl_xor(pm, off));
                nm = fminf(nm, __shfl_xor(nm, off));
            }
            if (l15 == 0) {
                int loc = wr * 64 + m * 16 + lhi * 4 + r;
                rowp[wc][loc] = pm;
                rown[wc][loc] = nm;
            }
        }
    }

    #pragma unroll
    for (int n = 0; n < 4; ++n) {
        int j   = j0 + wc * 64 + n * 16 + l15;
        int ljn = lj[n];
        float cp = 0.0f, cn = BIGF;
        #pragma unroll
        for (int m = 0; m < 4; ++m) {
            #pragma unroll
            for (int r = 0; r < 4; ++r) {
                float dist = fmaxf(1.0f - acc[m][n][r], 0.0f);
                int i = i0 + wr * 64 + m * 16 + lhi * 4 + r;
                if (li[m * 4 + r] == ljn) {
                    if (i != j) cp = fmaxf(cp, dist);
                } else {
                    cn = fminf(cn, dist);
                }
            }
        }
        #pragma unroll
        for (int off = 16; off < 64; off <<= 1) {
            cp = fmaxf(cp, __shfl_xor(cp, off));
            cn = fminf(cn, __shfl_xor(cn, off));
        }
        if (lhi == 0) {
            int loc = wc * 64 + n * 16 + l15;
            colp[wr][loc] = cp;
            coln[wr][loc] = cn;
        }
    }

    __syncthreads();

    if (tid < BM) {
        float pmv = fmaxf(rowp[0][tid], rowp[1][tid]);
        float nmv = fminf(rown[0][tid], rown[1][tid]);
        atomicMax(hp + i0 + tid, __float_as_uint(pmv));
        atomicMin(hn + i0 + tid, __float_as_uint(nmv));
    } else {
        int c = tid - BM;
        float pmv = fmaxf(colp[0][c], colp[1][c]);
        float nmv = fminf(coln[0][c], coln[1][c]);
        atomicMax(hp + j0 + c, __float_as_uint(pmv));
        atomicMin(hn + j0 + c, __float_as_uint(nmv));
    }
}

// ---------------- kernel 3: finalize ----------------
__global__ __launch_bounds__(1024) void final_k(const int* __restrict__ lab,
                                                const unsigned* __restrict__ hp,
                                                const unsigned* __restrict__ hn,
                                                float* __restrict__ out) {
    __shared__ int   cnt[NLBL];
    __shared__ float ssum[16];
    __shared__ int   scnt[16];
    int t = threadIdx.x;
    for (int i = t; i < NLBL; i += 1024) cnt[i] = 0;
    __syncthreads();
    for (int i = t; i < BATCH; i += 1024) atomicAdd(&cnt[lab[i]], 1);
    __syncthreads();

    float lsum = 0.0f;
    int   lcnt = 0;
    for (int i = t; i < BATCH; i += 1024) {
        int c = cnt[lab[i]];
        if ((c > 1) && (c < BATCH)) {
            float per = fmaxf(__uint_as_float(hp[i]) - __uint_as_float(hn[i]) + MARGIN, 0.0f);
            lsum += per;
            lcnt += 1;
        }
    }
    #pragma unroll
    for (int off = 1; off < 64; off <<= 1) {
        lsum += __shfl_xor(lsum, off);
        lcnt += __shfl_xor(lcnt, off);
    }
    int w = t >> 6;
    if ((t & 63) == 0) { ssum[w] = lsum; scnt[w] = lcnt; }
    __syncthreads();
    if (t == 0) {
        float s = 0.0f; int c2 = 0;
        #pragma unroll
        for (int i = 0; i < 16; ++i) { s += ssum[i]; c2 += scnt[i]; }
        out[0] = s / (float)max(c2, 1);
    }
}

// ---------------- launcher ----------------
extern "C" void kernel_launch(void* const* d_in, const int* in_sizes, int n_in,
                              void* d_out, int out_size, void* d_ws, size_t ws_size,
                              hipStream_t stream) {
    const float* emb = (const float*)d_in[0];
    const int*   lab = (const int*)d_in[1];

    char* base = (char*)d_ws;
    unsigned short* Hi = (unsigned short*)base;                       // 4 MB
    unsigned* hp = (unsigned*)(base + (size_t)BATCH * DIM * 2);       // 16 KB
    unsigned* hn = hp + BATCH;                                        // 16 KB

    normalize_k<<<BATCH / 4, 256, 0, stream>>>(emb, Hi, hp, hn);
    mine_k<<<NPAIR, 256, 0, stream>>>(Hi, lab, hp, hn);
    final_k<<<1, 1024, 0, stream>>>(lab, hp, hn, (float*)d_out);
}

// Round 6
// 40.905 us; speedup vs baseline: 1.7298x; 1.0245x over previous
//
#include <hip/hip_runtime.h>
#include <hip/hip_bf16.h>

#define BATCH 4096
#define DIM   512
#define NLBL  512
#define BIGF  1e4f
#define MARGIN 1.0f

#define BM 128        // tile (rows = cols)
#define BK 64         // bf16 elems per K-step
#define NT (BATCH/BM) // 32
#define NPAIR (NT*(NT+1)/2)  // 528
#define KITERS (DIM/BK)      // 8

using f32x4  = __attribute__((ext_vector_type(4))) float;
using bf16x8 = __attribute__((ext_vector_type(8))) short;

__device__ __forceinline__ unsigned short f2bf(float x) {
    __hip_bfloat16 h = __float2bfloat16(x);
    return *reinterpret_cast<unsigned short*>(&h);
}

#define GLOAD16(gp, lp) \
    __builtin_amdgcn_global_load_lds((const __attribute__((address_space(1))) void*)(gp), \
                                     (__attribute__((address_space(3))) void*)(lp), 16, 0, 0)

// ---------------- kernel 1: row L2-normalize -> bf16 (+ hp/hn init fused) ----------------
__global__ __launch_bounds__(256) void normalize_k(const float* __restrict__ emb,
                                                   unsigned short* __restrict__ Hi,
                                                   unsigned* __restrict__ hp,
                                                   unsigned* __restrict__ hn) {
    int wave = threadIdx.x >> 6;
    int lane = threadIdx.x & 63;
    int row  = blockIdx.x * 4 + wave;
    const float4* src = (const float4*)(emb + (size_t)row * DIM);
    float4 v0 = src[lane * 2];
    float4 v1 = src[lane * 2 + 1];
    float ss = v0.x*v0.x + v0.y*v0.y + v0.z*v0.z + v0.w*v0.w
             + v1.x*v1.x + v1.y*v1.y + v1.z*v1.z + v1.w*v1.w;
    #pragma unroll
    for (int off = 1; off < 64; off <<= 1) ss += __shfl_xor(ss, off);
    float scale = 1.0f / fmaxf(sqrtf(ss), 1e-12f);
    bf16x8 o;
    o[0] = (short)f2bf(v0.x * scale);
    o[1] = (short)f2bf(v0.y * scale);
    o[2] = (short)f2bf(v0.z * scale);
    o[3] = (short)f2bf(v0.w * scale);
    o[4] = (short)f2bf(v1.x * scale);
    o[5] = (short)f2bf(v1.y * scale);
    o[6] = (short)f2bf(v1.z * scale);
    o[7] = (short)f2bf(v1.w * scale);
    *(bf16x8*)(Hi + (size_t)row * DIM + lane * 8) = o;
    if (lane == 0) {
        hp[row] = 0u;
        hn[row] = __float_as_uint(BIGF);
    }
}

// ---------------- kernel 2: fused bf16 MFMA sim + batch-hard mining ----------------
// Upper-triangle 128x128 tiles. 8 waves/block (2x4: each wave 64x32 output),
// double-buffered LDS, counted-vmcnt pipeline (4 loads/wave/step stay in
// flight across barriers). 70KB LDS -> 2 blocks/CU = 16 waves/CU.
__global__ __launch_bounds__(512, 4) void mine_k(const unsigned short* __restrict__ Hi,
                                                 const int* __restrict__ lab,
                                                 unsigned* __restrict__ hp,
                                                 unsigned* __restrict__ hn) {
    __shared__ __attribute__((aligned(16))) unsigned short As[2][BM * BK]; // 32 KB
    __shared__ __attribute__((aligned(16))) unsigned short Bs[2][BM * BK]; // 32 KB
    __shared__ float rowp[4][BM], rown[4][BM];                             // 4 KB
    __shared__ float colp[2][BM], coln[2][BM];                             // 2 KB

    // XCD-aware swizzle (528 = 8*66, bijective)
    int p = (int)blockIdx.x;
    p = (p & 7) * (NPAIR / 8) + (p >> 3);
    int bi = 0, rem = p;
    while (rem >= NT - bi) { rem -= NT - bi; ++bi; }
    int bj = bi + rem;
    const int i0 = bi * BM;
    const int j0 = bj * BM;

    const int tid  = threadIdx.x;
    const int w    = tid >> 6;      // wave 0..7
    const int lane = tid & 63;
    const int wr   = w >> 2;        // 0..1 : 64-row half
    const int wc   = w & 3;         // 0..3 : 32-col quarter
    const int l15  = lane & 15;
    const int lhi  = lane >> 4;     // 0..3
    const int l7   = lane & 7;

    const int srow = lane >> 3;               // 0..7
    const int sc   = (lane & 7) ^ (srow & 7); // pre-swizzled 16B chunk

    f32x4 acc[4][2] = {};
    const char* HiB = (const char*)Hi;

    auto STAGE = [&](int buf, int t) {
        const size_t kb = (size_t)t * (BK * 2);
        #pragma unroll
        for (int q = 0; q < 2; ++q) {
            int r8 = w * 16 + q * 8;           // this wave's 16-row slice
            const char* ga = HiB + (size_t)(i0 + r8 + srow) * (DIM * 2) + kb + (sc << 4);
            const char* gb = HiB + (size_t)(j0 + r8 + srow) * (DIM * 2) + kb + (sc << 4);
            GLOAD16(ga, (char*)As[buf] + r8 * 128);
            GLOAD16(gb, (char*)Bs[buf] + r8 * 128);
        }
    };
    auto COMPUTE = [&](int buf) {
        #pragma unroll
        for (int kk = 0; kk < 2; ++kk) {
            bf16x8 a[4], b[2];
            #pragma unroll
            for (int m = 0; m < 4; ++m) {
                int row = wr * 64 + m * 16 + l15;
                int cp  = ((kk * 4 + lhi) ^ l7);
                a[m] = *(const bf16x8*)((const char*)As[buf] + row * 128 + (cp << 4));
            }
            #pragma unroll
            for (int n = 0; n < 2; ++n) {
                int row = wc * 32 + n * 16 + l15;
                int cp  = ((kk * 4 + lhi) ^ l7);
                b[n] = *(const bf16x8*)((const char*)Bs[buf] + row * 128 + (cp << 4));
            }
            #pragma unroll
            for (int m = 0; m < 4; ++m)
                #pragma unroll
                for (int n = 0; n < 2; ++n)
                    acc[m][n] = __builtin_amdgcn_mfma_f32_16x16x32_bf16(a[m], b[n], acc[m][n], 0, 0, 0);
        }
    };

    // ---- counted-vmcnt double-buffer pipeline ----
    STAGE(0, 0);
    STAGE(1, 1);      // 8 loads in flight per wave
    #pragma unroll
    for (int t = 0; t < KITERS; ++t) {
        const int cur = t & 1;
        if (t < KITERS - 1) {
            asm volatile("s_waitcnt vmcnt(4)" ::: "memory");  // batch t landed; t+1 stays in flight
        } else {
            asm volatile("s_waitcnt vmcnt(0)" ::: "memory");
        }
        __builtin_amdgcn_sched_barrier(0);
        __builtin_amdgcn_s_barrier();      // buf cur fully written (all waves)
        COMPUTE(cur);
        __builtin_amdgcn_sched_barrier(0);
        __builtin_amdgcn_s_barrier();      // all waves done reading buf cur
        if (t + 2 < KITERS) STAGE(cur, t + 2);
    }

    // ---- labels (after K-loop so they don't pollute vmcnt counts) ----
    int lj[2];
    #pragma unroll
    for (int n = 0; n < 2; ++n) lj[n] = lab[j0 + wc * 32 + n * 16 + l15];
    int li[16];
    #pragma unroll
    for (int m = 0; m < 4; ++m)
        #pragma unroll
        for (int r = 0; r < 4; ++r)
            li[m * 4 + r] = lab[i0 + wr * 64 + m * 16 + lhi * 4 + r];

    // ---- epilogue ----
    // C[i][j]: i = i0 + wr*64 + m*16 + lhi*4 + r ; j = j0 + wc*32 + n*16 + l15
    #pragma unroll
    for (int m = 0; m < 4; ++m) {
        #pragma unroll
        for (int r = 0; r < 4; ++r) {
            int i   = i0 + wr * 64 + m * 16 + lhi * 4 + r;
            int lir = li[m * 4 + r];
            float pm = 0.0f, nm = BIGF;
            #pragma unroll
            for (int n = 0; n < 2; ++n) {
                float dist = fmaxf(1.0f - acc[m][n][r], 0.0f);
                int j = j0 + wc * 32 + n * 16 + l15;
                if (lir == lj[n]) {
                    if (i != j) pm = fmaxf(pm, dist);
                } else {
                    nm = fminf(nm, dist);
                }
            }
            #pragma unroll
            for (int off = 1; off < 16; off <<= 1) {
                pm = fmaxf(pm, __shfl_xor(pm, off));
                nm = fminf(nm, __shfl_xor(nm, off));
            }
            if (l15 == 0) {
                int loc = wr * 64 + m * 16 + lhi * 4 + r;
                rowp[wc][loc] = pm;
                rown[wc][loc] = nm;
            }
        }
    }

    #pragma unroll
    for (int n = 0; n < 2; ++n) {
        int j   = j0 + wc * 32 + n * 16 + l15;
        int ljn = lj[n];
        float cp = 0.0f, cn = BIGF;
        #pragma unroll
        for (int m = 0; m < 4; ++m) {
            #pragma unroll
            for (int r = 0; r < 4; ++r) {
                float dist = fmaxf(1.0f - acc[m][n][r], 0.0f);
                int i = i0 + wr * 64 + m * 16 + lhi * 4 + r;
                if (li[m * 4 + r] == ljn) {
                    if (i != j) cp = fmaxf(cp, dist);
                } else {
                    cn = fminf(cn, dist);
                }
            }
        }
        #pragma unroll
        for (int off = 16; off < 64; off <<= 1) {
            cp = fmaxf(cp, __shfl_xor(cp, off));
            cn = fminf(cn, __shfl_xor(cn, off));
        }
        if (lhi == 0) {
            int loc = wc * 32 + n * 16 + l15;
            colp[wr][loc] = cp;
            coln[wr][loc] = cn;
        }
    }

    __syncthreads();

    if (tid < BM) {
        float pmv = fmaxf(fmaxf(rowp[0][tid], rowp[1][tid]), fmaxf(rowp[2][tid], rowp[3][tid]));
        float nmv = fminf(fminf(rown[0][tid], rown[1][tid]), fminf(rown[2][tid], rown[3][tid]));
        atomicMax(hp + i0 + tid, __float_as_uint(pmv));
        atomicMin(hn + i0 + tid, __float_as_uint(nmv));
    } else if (tid < 2 * BM) {
        int c = tid - BM;
        float pmv = fmaxf(colp[0][c], colp[1][c]);
        float nmv = fminf(coln[0][c], coln[1][c]);
        atomicMax(hp + j0 + c, __float_as_uint(pmv));
        atomicMin(hn + j0 + c, __float_as_uint(nmv));
    }
}

// ---------------- kernel 3: finalize ----------------
__global__ __launch_bounds__(1024) void final_k(const int* __restrict__ lab,
                                                const unsigned* __restrict__ hp,
                                                const unsigned* __restrict__ hn,
                                                float* __restrict__ out) {
    __shared__ int   cnt[NLBL];
    __shared__ float ssum[16];
    __shared__ int   scnt[16];
    int t = threadIdx.x;
    for (int i = t; i < NLBL; i += 1024) cnt[i] = 0;
    __syncthreads();
    for (int i = t; i < BATCH; i += 1024) atomicAdd(&cnt[lab[i]], 1);
    __syncthreads();

    float lsum = 0.0f;
    int   lcnt = 0;
    for (int i = t; i < BATCH; i += 1024) {
        int c = cnt[lab[i]];
        if ((c > 1) && (c < BATCH)) {
            float per = fmaxf(__uint_as_float(hp[i]) - __uint_as_float(hn[i]) + MARGIN, 0.0f);
            lsum += per;
            lcnt += 1;
        }
    }
    #pragma unroll
    for (int off = 1; off < 64; off <<= 1) {
        lsum += __shfl_xor(lsum, off);
        lcnt += __shfl_xor(lcnt, off);
    }
    int w = t >> 6;
    if ((t & 63) == 0) { ssum[w] = lsum; scnt[w] = lcnt; }
    __syncthreads();
    if (t == 0) {
        float s = 0.0f; int c2 = 0;
        #pragma unroll
        for (int i = 0; i < 16; ++i) { s += ssum[i]; c2 += scnt[i]; }
        out[0] = s / (float)max(c2, 1);
    }
}

// ---------------- launcher ----------------
extern "C" void kernel_launch(void* const* d_in, const int* in_sizes, int n_in,
                              void* d_out, int out_size, void* d_ws, size_t ws_size,
                              hipStream_t stream) {
    const float* emb = (const float*)d_in[0];
    const int*   lab = (const int*)d_in[1];

    char* base = (char*)d_ws;
    unsigned short* Hi = (unsigned short*)base;                       // 4 MB
    unsigned* hp = (unsigned*)(base + (size_t)BATCH * DIM * 2);       // 16 KB
    unsigned* hn = hp + BATCH;                                        // 16 KB

    normalize_k<<<BATCH / 4, 256, 0, stream>>>(emb, Hi, hp, hn);
    mine_k<<<NPAIR, 512, 0, stream>>>(Hi, lab, hp, hn);
    final_k<<<1, 1024, 0, stream>>>(lab, hp, hn, (float*)d_out);
}

// Round 7
// 36.367 us; speedup vs baseline: 1.9457x; 1.1248x over previous
//
#include <hip/hip_runtime.h>
#include <hip/hip_bf16.h>

#define BATCH 4096
#define DIM   512
#define NLBL  512
#define BIGF  1e4f
#define MARGIN 1.0f

#define BM 128        // tile (rows = cols)
#define BK 32         // bf16 elems per K-step (small -> 36KB LDS -> 4 blocks/CU)
#define NT (BATCH/BM) // 32
#define NPAIR (NT*(NT+1)/2)  // 528
#define KITERS (DIM/BK)      // 16

using f32x4  = __attribute__((ext_vector_type(4))) float;
using bf16x8 = __attribute__((ext_vector_type(8))) short;

__device__ __forceinline__ unsigned short f2bf(float x) {
    __hip_bfloat16 h = __float2bfloat16(x);
    return *reinterpret_cast<unsigned short*>(&h);
}

#define GLOAD16(gp, lp) \
    __builtin_amdgcn_global_load_lds((const __attribute__((address_space(1))) void*)(gp), \
                                     (__attribute__((address_space(3))) void*)(lp), 16, 0, 0)

// ---------------- kernel 1: row L2-normalize -> bf16 (+ hp/hn init fused) ----------------
__global__ __launch_bounds__(256) void normalize_k(const float* __restrict__ emb,
                                                   unsigned short* __restrict__ Hi,
                                                   unsigned* __restrict__ hp,
                                                   unsigned* __restrict__ hn) {
    int wave = threadIdx.x >> 6;
    int lane = threadIdx.x & 63;
    int row  = blockIdx.x * 4 + wave;
    const float4* src = (const float4*)(emb + (size_t)row * DIM);
    float4 v0 = src[lane * 2];
    float4 v1 = src[lane * 2 + 1];
    float ss = v0.x*v0.x + v0.y*v0.y + v0.z*v0.z + v0.w*v0.w
             + v1.x*v1.x + v1.y*v1.y + v1.z*v1.z + v1.w*v1.w;
    #pragma unroll
    for (int off = 1; off < 64; off <<= 1) ss += __shfl_xor(ss, off);
    float scale = 1.0f / fmaxf(sqrtf(ss), 1e-12f);
    bf16x8 o;
    o[0] = (short)f2bf(v0.x * scale);
    o[1] = (short)f2bf(v0.y * scale);
    o[2] = (short)f2bf(v0.z * scale);
    o[3] = (short)f2bf(v0.w * scale);
    o[4] = (short)f2bf(v1.x * scale);
    o[5] = (short)f2bf(v1.y * scale);
    o[6] = (short)f2bf(v1.z * scale);
    o[7] = (short)f2bf(v1.w * scale);
    *(bf16x8*)(Hi + (size_t)row * DIM + lane * 8) = o;
    if (lane == 0) {
        hp[row] = 0u;
        hn[row] = __float_as_uint(BIGF);
    }
}

// ---------------- kernel 2: fused bf16 MFMA sim + batch-hard mining ----------------
// Upper-triangle 128x128 tiles, BK=32 double-buffered (36KB LDS -> 4 blocks/CU,
// ALL 528 blocks co-resident: no dispatch generations, no tail). 4 waves (2x2),
// counted-vmcnt pipeline: 4 loads/wave/step stay in flight across barriers.
__global__ __launch_bounds__(256, 4) void mine_k(const unsigned short* __restrict__ Hi,
                                                 const int* __restrict__ lab,
                                                 unsigned* __restrict__ hp,
                                                 unsigned* __restrict__ hn) {
    __shared__ __attribute__((aligned(16))) unsigned short As[2][BM * BK]; // 16 KB
    __shared__ __attribute__((aligned(16))) unsigned short Bs[2][BM * BK]; // 16 KB
    __shared__ float rowp[2][BM], rown[2][BM], colp[2][BM], coln[2][BM];   // 4 KB

    // XCD-aware swizzle (528 = 8*66, bijective)
    int p = (int)blockIdx.x;
    p = (p & 7) * (NPAIR / 8) + (p >> 3);
    int bi = 0, rem = p;
    while (rem >= NT - bi) { rem -= NT - bi; ++bi; }
    int bj = bi + rem;
    const int i0 = bi * BM;
    const int j0 = bj * BM;

    const int tid  = threadIdx.x;
    const int w    = tid >> 6;
    const int lane = tid & 63;
    const int wr   = w >> 1;
    const int wc   = w & 1;
    const int l15  = lane & 15;
    const int lhi  = lane >> 4;     // 0..3 : 16B k-chunk within 64B row

    f32x4 acc[4][4] = {};
    const char* HiB = (const char*)Hi;

    // stage: per wave 2 instrs/matrix; instr covers 16 rows x 64B.
    // lane l -> row +(l>>2), phys chunk l&3 holds logical (l&3)^((row>>1)&3).
    auto STAGE = [&](int buf, int t) {
        const size_t kb = (size_t)t * (BK * 2);
        #pragma unroll
        for (int q = 0; q < 2; ++q) {
            int r16 = w * 32 + q * 16;
            int lr  = r16 + (lane >> 2);
            int sc  = (lane & 3) ^ ((lr >> 1) & 3);
            const char* ga = HiB + (size_t)(i0 + lr) * (DIM * 2) + kb + (sc << 4);
            const char* gb = HiB + (size_t)(j0 + lr) * (DIM * 2) + kb + (sc << 4);
            GLOAD16(ga, (char*)As[buf] + r16 * 64);
            GLOAD16(gb, (char*)Bs[buf] + r16 * 64);
        }
    };
    // compute: one MFMA K-slice per step (BK=32). 2-way bank aliasing max (free).
    auto COMPUTE = [&](int buf) {
        bf16x8 a[4], b[4];
        #pragma unroll
        for (int m = 0; m < 4; ++m) {
            int row = wr * 64 + m * 16 + l15;
            int cp  = lhi ^ ((row >> 1) & 3);
            a[m] = *(const bf16x8*)((const char*)As[buf] + row * 64 + (cp << 4));
        }
        #pragma unroll
        for (int n = 0; n < 4; ++n) {
            int row = wc * 64 + n * 16 + l15;
            int cp  = lhi ^ ((row >> 1) & 3);
            b[n] = *(const bf16x8*)((const char*)Bs[buf] + row * 64 + (cp << 4));
        }
        #pragma unroll
        for (int m = 0; m < 4; ++m)
            #pragma unroll
            for (int n = 0; n < 4; ++n)
                acc[m][n] = __builtin_amdgcn_mfma_f32_16x16x32_bf16(a[m], b[n], acc[m][n], 0, 0, 0);
    };

    // ---- counted-vmcnt double-buffer pipeline ----
    STAGE(0, 0);
    STAGE(1, 1);      // 8 loads in flight per wave
    #pragma unroll
    for (int t = 0; t < KITERS; ++t) {
        const int cur = t & 1;
        if (t < KITERS - 1) {
            asm volatile("s_waitcnt vmcnt(4)" ::: "memory");  // batch t landed; t+1 in flight
        } else {
            asm volatile("s_waitcnt vmcnt(0)" ::: "memory");
        }
        __builtin_amdgcn_sched_barrier(0);
        __builtin_amdgcn_s_barrier();      // buf cur fully written (all waves)
        COMPUTE(cur);
        __builtin_amdgcn_sched_barrier(0);
        __builtin_amdgcn_s_barrier();      // all waves done reading buf cur
        if (t + 2 < KITERS) STAGE(cur, t + 2);
    }

    // ---- labels (after K-loop so they don't pollute vmcnt counts) ----
    int lj[4];
    #pragma unroll
    for (int n = 0; n < 4; ++n) lj[n] = lab[j0 + wc * 64 + n * 16 + l15];
    int li[16];
    #pragma unroll
    for (int m = 0; m < 4; ++m)
        #pragma unroll
        for (int r = 0; r < 4; ++r)
            li[m * 4 + r] = lab[i0 + wr * 64 + m * 16 + lhi * 4 + r];

    // ---- epilogue ----
    // C[i][j]: i = i0 + wr*64 + m*16 + lhi*4 + r ; j = j0 + wc*64 + n*16 + l15
    #pragma unroll
    for (int m = 0; m < 4; ++m) {
        #pragma unroll
        for (int r = 0; r < 4; ++r) {
            int i   = i0 + wr * 64 + m * 16 + lhi * 4 + r;
            int lir = li[m * 4 + r];
            float pm = 0.0f, nm = BIGF;
            #pragma unroll
            for (int n = 0; n < 4; ++n) {
                float dist = fmaxf(1.0f - acc[m][n][r], 0.0f);
                int j = j0 + wc * 64 + n * 16 + l15;
                if (lir == lj[n]) {
                    if (i != j) pm = fmaxf(pm, dist);
                } else {
                    nm = fminf(nm, dist);
                }
            }
            #pragma unroll
            for (int off = 1; off < 16; off <<= 1) {
                pm = fmaxf(pm, __shfl_xor(pm, off));
                nm = fminf(nm, __shfl_xor(nm, off));
            }
            if (l15 == 0) {
                int loc = wr * 64 + m * 16 + lhi * 4 + r;
                rowp[wc][loc] = pm;
                rown[wc][loc] = nm;
            }
        }
    }

    #pragma unroll
    for (int n = 0; n < 4; ++n) {
        int j   = j0 + wc * 64 + n * 16 + l15;
        int ljn = lj[n];
        float cp = 0.0f, cn = BIGF;
        #pragma unroll
        for (int m = 0; m < 4; ++m) {
            #pragma unroll
            for (int r = 0; r < 4; ++r) {
                float dist = fmaxf(1.0f - acc[m][n][r], 0.0f);
                int i = i0 + wr * 64 + m * 16 + lhi * 4 + r;
                if (li[m * 4 + r] == ljn) {
                    if (i != j) cp = fmaxf(cp, dist);
                } else {
                    cn = fminf(cn, dist);
                }
            }
        }
        #pragma unroll
        for (int off = 16; off < 64; off <<= 1) {
            cp = fmaxf(cp, __shfl_xor(cp, off));
            cn = fminf(cn, __shfl_xor(cn, off));
        }
        if (lhi == 0) {
            int loc = wc * 64 + n * 16 + l15;
            colp[wr][loc] = cp;
            coln[wr][loc] = cn;
        }
    }

    __syncthreads();

    if (tid < BM) {
        float pmv = fmaxf(rowp[0][tid], rowp[1][tid]);
        float nmv = fminf(rown[0][tid], rown[1][tid]);
        atomicMax(hp + i0 + tid, __float_as_uint(pmv));
        atomicMin(hn + i0 + tid, __float_as_uint(nmv));
    } else {
        int c = tid - BM;
        float pmv = fmaxf(colp[0][c], colp[1][c]);
        float nmv = fminf(coln[0][c], coln[1][c]);
        atomicMax(hp + j0 + c, __float_as_uint(pmv));
        atomicMin(hn + j0 + c, __float_as_uint(nmv));
    }
}

// ---------------- kernel 3: finalize ----------------
__global__ __launch_bounds__(1024) void final_k(const int* __restrict__ lab,
                                                const unsigned* __restrict__ hp,
                                                const unsigned* __restrict__ hn,
                                                float* __restrict__ out) {
    __shared__ int   cnt[NLBL];
    __shared__ float ssum[16];
    __shared__ int   scnt[16];
    int t = threadIdx.x;
    for (int i = t; i < NLBL; i += 1024) cnt[i] = 0;
    __syncthreads();
    for (int i = t; i < BATCH; i += 1024) atomicAdd(&cnt[lab[i]], 1);
    __syncthreads();

    float lsum = 0.0f;
    int   lcnt = 0;
    for (int i = t; i < BATCH; i += 1024) {
        int c = cnt[lab[i]];
        if ((c > 1) && (c < BATCH)) {
            float per = fmaxf(__uint_as_float(hp[i]) - __uint_as_float(hn[i]) + MARGIN, 0.0f);
            lsum += per;
            lcnt += 1;
        }
    }
    #pragma unroll
    for (int off = 1; off < 64; off <<= 1) {
        lsum += __shfl_xor(lsum, off);
        lcnt += __shfl_xor(lcnt, off);
    }
    int w = t >> 6;
    if ((t & 63) == 0) { ssum[w] = lsum; scnt[w] = lcnt; }
    __syncthreads();
    if (t == 0) {
        float s = 0.0f; int c2 = 0;
        #pragma unroll
        for (int i = 0; i < 16; ++i) { s += ssum[i]; c2 += scnt[i]; }
        out[0] = s / (float)max(c2, 1);
    }
}

// ---------------- launcher ----------------
extern "C" void kernel_launch(void* const* d_in, const int* in_sizes, int n_in,
                              void* d_out, int out_size, void* d_ws, size_t ws_size,
                              hipStream_t stream) {
    const float* emb = (const float*)d_in[0];
    const int*   lab = (const int*)d_in[1];

    char* base = (char*)d_ws;
    unsigned short* Hi = (unsigned short*)base;                       // 4 MB
    unsigned* hp = (unsigned*)(base + (size_t)BATCH * DIM * 2);       // 16 KB
    unsigned* hn = hp + BATCH;                                        // 16 KB

    normalize_k<<<BATCH / 4, 256, 0, stream>>>(emb, Hi, hp, hn);
    mine_k<<<NPAIR, 256, 0, stream>>>(Hi, lab, hp, hn);
    final_k<<<1, 1024, 0, stream>>>(lab, hp, hn, (float*)d_out);
}